// Round 1
// baseline (347.216 us; speedup 1.0000x reference)
//
#include <hip/hip_runtime.h>

#define S_DEPTH 256
#define NRES 384
#define CIN 32
#define CZ 128
#define MDIM (NRES * CIN) /* 12288 */

typedef short bf16x8 __attribute__((ext_vector_type(8)));
typedef short short4v __attribute__((ext_vector_type(4)));
typedef float f32x4 __attribute__((ext_vector_type(4)));

static __device__ __forceinline__ unsigned short f2bf(float f) {
  unsigned int u = __float_as_uint(f);
  unsigned int r = (u + 0x7fffu + ((u >> 16) & 1u)) >> 16; // RNE
  return (unsigned short)r;
}

static __device__ __forceinline__ void gld16(const void* g, void* l) {
  __builtin_amdgcn_global_load_lds((__attribute__((address_space(1))) void*)(g),
                                   (__attribute__((address_space(3))) void*)(l),
                                   16, 0, 0);
}

// ---------------- kernel 0: W3 -> bf16, layout W3T[e][d*32 + c] ----------------
__global__ __launch_bounds__(256) void k_w3t(const float* __restrict__ W3,
                                             unsigned short* __restrict__ W3T) {
  int t = blockIdx.x * 256 + threadIdx.x; // 0..131071
  int e = t >> 10;
  int q = t & 1023;    // q' = d*32 + c
  int d = q >> 5, c = q & 31;
  W3T[t] = f2bf(W3[(c * 32 + d) * 128 + e]);
}

// ---------------- kernel 1: LayerNorm + W1/W2 proj -> aT, bT (bf16, [m][k=s]) ----
__global__ __launch_bounds__(256) void k_lnproj(
    const float* __restrict__ mm, const float* __restrict__ gamma,
    const float* __restrict__ beta, const float* __restrict__ W1,
    const float* __restrict__ W2, unsigned short* __restrict__ aT,
    unsigned short* __restrict__ bT) {
  __shared__ float buf[256 * 33]; // stride 33 to break bank alignment
  const int t = threadIdx.x;
  const int i = blockIdx.x;

  // stage m[s][i][0:32] for all s, coalesced 16B per lane
#pragma unroll
  for (int it = 0; it < 8; ++it) {
    int s = it * 32 + (t >> 3);
    int c4 = (t & 7) * 4;
    const float4 v = *(const float4*)(mm + ((size_t)s * NRES + i) * CIN + c4);
    buf[s * 33 + c4 + 0] = v.x;
    buf[s * 33 + c4 + 1] = v.y;
    buf[s * 33 + c4 + 2] = v.z;
    buf[s * 33 + c4 + 3] = v.w;
  }
  __syncthreads();

  // thread t owns MSA row s = t
  float x[32];
#pragma unroll
  for (int k = 0; k < 32; ++k) x[k] = buf[t * 33 + k];
  float mu = 0.f;
#pragma unroll
  for (int k = 0; k < 32; ++k) mu += x[k];
  mu *= (1.f / 32.f);
  float var = 0.f;
#pragma unroll
  for (int k = 0; k < 32; ++k) {
    float dk = x[k] - mu;
    var += dk * dk;
  }
  var *= (1.f / 32.f);
  float inv = rsqrtf(var + 1e-5f);
#pragma unroll
  for (int k = 0; k < 32; ++k) x[k] = (x[k] - mu) * inv * gamma[k] + beta[k];

  float va[32], vb[32];
#pragma unroll
  for (int c = 0; c < 32; ++c) {
    float sa = 0.f, sb = 0.f;
#pragma unroll
    for (int k = 0; k < 32; ++k) {
      sa += x[k] * W1[k * 32 + c]; // uniform -> s_load
      sb += x[k] * W2[k * 32 + c];
    }
    va[c] = sa;
    vb[c] = sb;
  }

  // transpose via LDS, write aT then bT: row (i*32+c), 256 k-contiguous bf16
  __syncthreads();
#pragma unroll
  for (int c = 0; c < 32; ++c) buf[t * 33 + c] = va[c];
  __syncthreads();
  {
    unsigned short* dst = aT + (size_t)i * 32 * 256;
#pragma unroll
    for (int rrep = 0; rrep < 4; ++rrep) {
      int id = rrep * 256 + t;
      int c = id >> 5, s8 = (id & 31) * 8;
      union { unsigned short us[8]; uint4 v; } pk;
#pragma unroll
      for (int j2 = 0; j2 < 8; ++j2) pk.us[j2] = f2bf(buf[(s8 + j2) * 33 + c]);
      *(uint4*)(dst + c * 256 + s8) = pk.v;
    }
  }
  __syncthreads();
#pragma unroll
  for (int c = 0; c < 32; ++c) buf[t * 33 + c] = vb[c];
  __syncthreads();
  {
    unsigned short* dst = bT + (size_t)i * 32 * 256;
#pragma unroll
    for (int rrep = 0; rrep < 4; ++rrep) {
      int id = rrep * 256 + t;
      int c = id >> 5, s8 = (id & 31) * 8;
      union { unsigned short us[8]; uint4 v; } pk;
#pragma unroll
      for (int j2 = 0; j2 < 8; ++j2) pk.us[j2] = f2bf(buf[(s8 + j2) * 33 + c]);
      *(uint4*)(dst + c * 256 + s8) = pk.v;
    }
  }
}

// ---------------- kernel 2: fused o-GEMM (128x256 tile, K=256) + W3 epilogue ----
__global__ __launch_bounds__(256, 2) void k_opm(
    const unsigned short* __restrict__ aT, const unsigned short* __restrict__ bT,
    const unsigned short* __restrict__ W3T, const float* __restrict__ b3,
    float* __restrict__ out) {
  __shared__ __align__(16) char smem[65536];
  const int t = threadIdx.x;
  const int w = t >> 6;      // wave 0..3
  const int l = t & 63;      // lane
  const int lr = l & 15;
  const int quad = l >> 4;
  const int wm = w >> 1, wn = w & 1; // wave tile: rows wm*64, cols wn*128
  const int m0 = blockIdx.y * 128;   // i-block (4 residues)
  const int n0 = blockIdx.x * 256;   // j-block (8 residues)

  f32x4 acc[4][8];
#pragma unroll
  for (int mt = 0; mt < 4; ++mt)
#pragma unroll
    for (int nt = 0; nt < 8; ++nt) {
      acc[mt][nt][0] = 0.f; acc[mt][nt][1] = 0.f;
      acc[mt][nt][2] = 0.f; acc[mt][nt][3] = 0.f;
    }

  char* smemB = smem + 8192;

  // ---- main K loop: o[m0..+127][n0..+255] += A-tile * B-tile ----
  for (int k0 = 0; k0 < 256; k0 += 32) {
    __syncthreads();
    // stage A-tile 128x32 (8KB), tile-chunked layout: 16-row tiles, each
    // [quad][row] chunk order so frag reads are tile_base + lane*16
#pragma unroll
    for (int p_ = 0; p_ < 2; ++p_) {
      int ch = p_ * 256 + t;
      int tile = ch >> 6, q = (ch >> 4) & 3, r = ch & 15;
      gld16(aT + (size_t)(m0 + tile * 16 + r) * 256 + k0 + q * 8,
            smem + p_ * 4096 + w * 1024);
    }
    // stage B-tile 256x32 (16KB)
#pragma unroll
    for (int p_ = 0; p_ < 4; ++p_) {
      int ch = p_ * 256 + t;
      int tile = ch >> 6, q = (ch >> 4) & 3, r = ch & 15;
      gld16(bT + (size_t)(n0 + tile * 16 + r) * 256 + k0 + q * 8,
            smemB + p_ * 4096 + w * 1024);
    }
    __syncthreads();

    bf16x8 af[4];
#pragma unroll
    for (int mt = 0; mt < 4; ++mt)
      af[mt] = *(const bf16x8*)(smem + (wm * 4 + mt) * 1024 + l * 16);
#pragma unroll
    for (int nt = 0; nt < 8; ++nt) {
      bf16x8 bfr = *(const bf16x8*)(smemB + (wn * 8 + nt) * 1024 + l * 16);
#pragma unroll
      for (int mt = 0; mt < 4; ++mt)
        acc[mt][nt] =
            __builtin_amdgcn_mfma_f32_16x16x32_bf16(af[mt], bfr, acc[mt][nt], 0, 0, 0);
    }
  }

  // ---- epilogue: repack o (bf16, /256) into o_lds[32 pairs][1024 q'] with
  // XOR chunk swizzle key=(p^d)&7 -> reads & writes <=2-way conflicts ----
  __syncthreads();
  const float scale = 1.0f / 256.0f;
#pragma unroll
  for (int mt = 0; mt < 4; ++mt) {
    int i_l = wm * 2 + (mt >> 1);
    int chc = 2 * (mt & 1) + (quad >> 1); // (c0>>3)
#pragma unroll
    for (int nt = 0; nt < 8; ++nt) {
      int j_l = wn * 4 + (nt >> 1);
      int d = (nt & 1) * 16 + lr;
      int p = i_l * 8 + j_l;
      int ch = d * 4 + chc;
      int key = (p ^ d) & 7;
      int off = p * 2048 + ((ch ^ key) << 4) + 8 * (quad & 1); // bytes
      short4v pk;
      pk[0] = (short)f2bf(acc[mt][nt][0] * scale);
      pk[1] = (short)f2bf(acc[mt][nt][1] * scale);
      pk[2] = (short)f2bf(acc[mt][nt][2] * scale);
      pk[3] = (short)f2bf(acc[mt][nt][3] * scale);
      *(short4v*)(smem + off) = pk;
    }
  }
  __syncthreads();

  // ---- z[p][e] = sum_q o[p][q'] * W3T[e][q'] ; wave w owns e-tiles {2w,2w+1}
  f32x4 zacc[2][2];
#pragma unroll
  for (int a = 0; a < 2; ++a)
#pragma unroll
    for (int b = 0; b < 2; ++b) {
      zacc[a][b][0] = 0.f; zacc[a][b][1] = 0.f;
      zacc[a][b][2] = 0.f; zacc[a][b][3] = 0.f;
    }
  float bias0 = b3[(w * 2 + 0) * 16 + lr];
  float bias1 = b3[(w * 2 + 1) * 16 + lr];

#pragma unroll 4
  for (int kq = 0; kq < 32; ++kq) {
    bf16x8 aef[2];
#pragma unroll
    for (int mte = 0; mte < 2; ++mte) {
      int row = mte * 16 + lr;
      int ch = kq * 4 + quad;
      int key = (row ^ kq) & 7;
      aef[mte] = *(const bf16x8*)(smem + row * 2048 + ((ch ^ key) << 4));
    }
#pragma unroll
    for (int nte = 0; nte < 2; ++nte) {
      const unsigned short* wg =
          W3T + (size_t)((w * 2 + nte) * 16 + lr) * 1024 + kq * 32 + quad * 8;
      bf16x8 bfr = *(const bf16x8*)wg;
#pragma unroll
      for (int mte = 0; mte < 2; ++mte)
        zacc[mte][nte] =
            __builtin_amdgcn_mfma_f32_16x16x32_bf16(aef[mte], bfr, zacc[mte][nte], 0, 0, 0);
    }
  }

  const int i0 = blockIdx.y * 4, j0 = blockIdx.x * 8;
#pragma unroll
  for (int mte = 0; mte < 2; ++mte)
#pragma unroll
    for (int nte = 0; nte < 2; ++nte) {
      int e = (w * 2 + nte) * 16 + lr;
      float bias = nte ? bias1 : bias0;
#pragma unroll
      for (int r = 0; r < 4; ++r) {
        int p = mte * 16 + quad * 4 + r;
        out[(((size_t)(i0 + (p >> 3))) * NRES + (j0 + (p & 7))) * CZ + e] =
            zacc[mte][nte][r] + bias;
      }
    }
}

// ---------------- host launch ----------------
extern "C" void kernel_launch(void* const* d_in, const int* in_sizes, int n_in,
                              void* d_out, int out_size, void* d_ws, size_t ws_size,
                              hipStream_t stream) {
  const float* m = (const float*)d_in[0];
  const float* gamma = (const float*)d_in[1];
  const float* beta = (const float*)d_in[2];
  const float* W1 = (const float*)d_in[3];
  const float* W2 = (const float*)d_in[4];
  const float* W3 = (const float*)d_in[5];
  const float* b3 = (const float*)d_in[6];
  float* out = (float*)d_out;

  unsigned short* aT = (unsigned short*)d_ws;                 // 12288 x 256 bf16
  unsigned short* bT = aT + (size_t)MDIM * S_DEPTH;           // 12288 x 256 bf16
  unsigned short* W3T = bT + (size_t)MDIM * S_DEPTH;          // 128 x 1024 bf16

  k_w3t<<<512, 256, 0, stream>>>(W3, W3T);
  k_lnproj<<<NRES, 256, 0, stream>>>(m, gamma, beta, W1, W2, aT, bT);
  k_opm<<<dim3(48, 96), 256, 0, stream>>>(aT, bT, W3T, b3, out);
}